// Round 2
// baseline (394.324 us; speedup 1.0000x reference)
//
#include <hip/hip_runtime.h>
#include <hip/hip_bf16.h>

// Problem: B=4, L=2048, C=1024, H=16, D=64, M=B*L=8192
// I/O dtype: float32 (reference dtypes; round-1 NaN proved f32-as-bf16 misread).
// Internal compute: bf16 MFMA with f32 accumulate (2% threshold permits).

typedef __attribute__((ext_vector_type(8))) short bf16x8;   // 8 bf16 = 4 VGPRs (MFMA A/B frag)
typedef __attribute__((ext_vector_type(4))) float f32x4;    // MFMA C/D frag

#define MAXLOG 4.60517018598809f  // ln(100)

__device__ __forceinline__ float bf2f(unsigned short u) {
    union { unsigned int i; float f; } v; v.i = ((unsigned int)u) << 16; return v.f;
}
__device__ __forceinline__ unsigned short f2bf(float f) {
    union { float f; unsigned int i; } v; v.f = f;
    unsigned int x = v.i;
    return (unsigned short)((x + 0x7FFFu + ((x >> 16) & 1u)) >> 16);  // RNE
}

// pack 8 consecutive f32 -> bf16x8 (two float4 loads)
__device__ __forceinline__ bf16x8 pack8(const float* __restrict__ p) {
    float4 a = *(const float4*)p;
    float4 b = *(const float4*)(p + 4);
    bf16x8 r;
    r[0] = (short)f2bf(a.x); r[1] = (short)f2bf(a.y);
    r[2] = (short)f2bf(a.z); r[3] = (short)f2bf(a.w);
    r[4] = (short)f2bf(b.x); r[5] = (short)f2bf(b.y);
    r[6] = (short)f2bf(b.z); r[7] = (short)f2bf(b.w);
    return r;
}

// ---------------------------------------------------------------- bias build
__global__ void k_build_bias(const float* __restrict__ qb,
                             const float* __restrict__ vb,
                             float* __restrict__ bias3) {
    int i = blockIdx.x * 256 + threadIdx.x;
    if (i < 3072) {
        float v = 0.0f;
        if (i < 1024) v = qb[i];
        else if (i >= 2048) v = vb[i - 2048];
        bias3[i] = v;
    }
}

// ------------------------------------------------- GEMM (B-transposed input)
// C[m][n] = sum_k A[m][k] * Bm[n][k] + bias[n]
// A: [M,K] (f32 or bf16 per template), Bm: [N,K] f32, out f32 or bf16.
// 128x128 tile / 256 threads (4 waves, each 64x64 = 4x4 MFMA 16x16x32 tiles)
template<bool A_F32, bool OUT_F32>
__global__ __launch_bounds__(256) void k_gemm_bt(
    const void* __restrict__ Ap, const float* __restrict__ Bm,
    const float* __restrict__ bias, void* __restrict__ Cp,
    int N, int K)
{
    __shared__ unsigned short As[128 * 32];
    __shared__ unsigned short Bs[128 * 32];
    const int t = threadIdx.x;
    const int wave = t >> 6, lane = t & 63;
    const int quad = lane >> 4, l16 = lane & 15;
    const int bm = blockIdx.x * 128, bn = blockIdx.y * 128;
    const int wr = (wave >> 1) * 64, wc = (wave & 1) * 64;

    f32x4 acc[4][4] = {};

    const int sr = t >> 2;          // 0..63 staging row
    const int sc = (t & 3) * 8;     // 0,8,16,24 staging col (elems)
    const long aoff0 = (long)(bm + sr) * K + sc;
    const long aoff1 = (long)(bm + sr + 64) * K + sc;
    const long boff0 = (long)(bn + sr) * K + sc;
    const long boff1 = (long)(bn + sr + 64) * K + sc;

    for (int kt = 0; kt < K; kt += 32) {
        __syncthreads();
        if (A_F32) {
            const float* A = (const float*)Ap;
            *(bf16x8*)&As[sr * 32 + sc]        = pack8(&A[aoff0 + kt]);
            *(bf16x8*)&As[(sr + 64) * 32 + sc] = pack8(&A[aoff1 + kt]);
        } else {
            const unsigned short* A = (const unsigned short*)Ap;
            *(bf16x8*)&As[sr * 32 + sc]        = *(const bf16x8*)&A[aoff0 + kt];
            *(bf16x8*)&As[(sr + 64) * 32 + sc] = *(const bf16x8*)&A[aoff1 + kt];
        }
        *(bf16x8*)&Bs[sr * 32 + sc]        = pack8(&Bm[boff0 + kt]);
        *(bf16x8*)&Bs[(sr + 64) * 32 + sc] = pack8(&Bm[boff1 + kt]);
        __syncthreads();
        bf16x8 af[4], bfr[4];
        for (int i = 0; i < 4; ++i)
            af[i] = *(const bf16x8*)&As[(wr + i * 16 + l16) * 32 + quad * 8];
        for (int j = 0; j < 4; ++j)
            bfr[j] = *(const bf16x8*)&Bs[(wc + j * 16 + l16) * 32 + quad * 8];
        for (int i = 0; i < 4; ++i)
            for (int j = 0; j < 4; ++j)
                acc[i][j] = __builtin_amdgcn_mfma_f32_16x16x32_bf16(af[i], bfr[j], acc[i][j], 0, 0, 0);
    }
    // epilogue: C/D layout col=lane&15, row=quad*4+reg
    for (int j = 0; j < 4; ++j) {
        int gn = bn + wc + j * 16 + l16;
        float bv = bias[gn];
        for (int i = 0; i < 4; ++i) {
            int gm0 = bm + wr + i * 16 + quad * 4;
            for (int r = 0; r < 4; ++r) {
                float val = acc[i][j][r] + bv;
                if (OUT_F32) ((float*)Cp)[(long)(gm0 + r) * N + gn] = val;
                else ((unsigned short*)Cp)[(long)(gm0 + r) * N + gn] = f2bf(val);
            }
        }
    }
}

// ------------------------------------------- q,k L2-normalize + head reshape
// qkv:[8192,3072] bf16 -> qb,kb:[B,H,L,D] bf16 (q scaled by exp(min(sml,ln100)))
__global__ __launch_bounds__(256) void k_norm_qk(
    const unsigned short* __restrict__ qkv, const float* __restrict__ sml,
    unsigned short* __restrict__ qb, unsigned short* __restrict__ kb)
{
    const int wid = blockIdx.x * 4 + (threadIdx.x >> 6);
    const int lane = threadIdx.x & 63;
    const int h = wid & 15;
    const int m = wid >> 4;           // 0..8191 (= b*2048 + l)
    const int b = m >> 11, l = m & 2047;
    float qv = bf2f(qkv[(long)m * 3072 + h * 64 + lane]);
    float kv = bf2f(qkv[(long)m * 3072 + 1024 + h * 64 + lane]);
    float sq = qv * qv, sk = kv * kv;
    for (int s = 32; s; s >>= 1) {
        sq += __shfl_xor(sq, s, 64);
        sk += __shfl_xor(sk, s, 64);
    }
    float scale = __expf(fminf(sml[h], MAXLOG));
    float qn = qv * (scale / fmaxf(sqrtf(sq), 1e-12f));
    float kn = kv / fmaxf(sqrtf(sk), 1e-12f);
    long o = ((long)(b * 16 + h) * 2048 + l) * 64 + lane;
    qb[o] = f2bf(qn);
    kb[o] = f2bf(kn);
}

// --------------------------------------------------- v transpose to [B,H,D,L]
__global__ __launch_bounds__(256) void k_vtrans(
    const unsigned short* __restrict__ qkv, unsigned short* __restrict__ vT)
{
    __shared__ unsigned short Vs[64 * 72];
    const int t = threadIdx.x;
    const int bh = blockIdx.y;          // b*16+h
    const int l0 = blockIdx.x * 64;
    const int h = bh & 15, b = bh >> 4;
    const int ll = t >> 2, d0 = (t & 3) * 16;
    long src = (long)(b * 2048 + l0 + ll) * 3072 + 2048 + h * 64 + d0;
    *(bf16x8*)&Vs[ll * 72 + d0]     = *(const bf16x8*)&qkv[src];
    *(bf16x8*)&Vs[ll * 72 + d0 + 8] = *(const bf16x8*)&qkv[src + 8];
    __syncthreads();
    const int d = t >> 2, ls = (t & 3) * 16;
    unsigned short tmp[16];
    for (int j = 0; j < 16; ++j) tmp[j] = Vs[(ls + j) * 72 + d];
    long dst = (long)(bh * 64 + d) * 2048 + l0 + ls;
    *(bf16x8*)&vT[dst]     = *(bf16x8*)&tmp[0];
    *(bf16x8*)&vT[dst + 8] = *(bf16x8*)&tmp[8];
}

// ------------------------------------------------------------ flash attention
// q normalized*scale (|q|=scale), k unit-norm -> |s| <= scale. Constant shift
// c = scale (softmax shift-invariance) => single pass, no running max.
__global__ __launch_bounds__(256) void k_attn(
    const unsigned short* __restrict__ qb, const unsigned short* __restrict__ kb,
    const unsigned short* __restrict__ vT, const float* __restrict__ sml,
    unsigned short* __restrict__ attn)
{
    __shared__ unsigned short Ks[64 * 72];
    __shared__ unsigned short Vs[64 * 72];
    __shared__ unsigned short Ps[4 * 16 * 72];
    const int t = threadIdx.x;
    const int wave = t >> 6, lane = t & 63;
    const int quad = lane >> 4, l16 = lane & 15;
    const int bh = blockIdx.y, h = bh & 15;
    const int q0 = blockIdx.x * 64;
    const float scale = __expf(fminf(sml[h], MAXLOG));

    bf16x8 aq[2];
    {
        long base = ((long)bh * 2048 + q0 + wave * 16 + l16) * 64 + quad * 8;
        aq[0] = *(const bf16x8*)&qb[base];
        aq[1] = *(const bf16x8*)&qb[base + 32];
    }
    f32x4 o[4] = {};
    f32x4 lacc = {};
    bf16x8 ones;
    for (int i = 0; i < 8; ++i) ones[i] = (short)0x3F80;  // bf16 1.0

    const int sr = t >> 2, sc = (t & 3) * 16;
    for (int kt = 0; kt < 2048; kt += 64) {
        __syncthreads();
        {
            long ksrc = ((long)bh * 2048 + kt + sr) * 64 + sc;
            *(bf16x8*)&Ks[sr * 72 + sc]     = *(const bf16x8*)&kb[ksrc];
            *(bf16x8*)&Ks[sr * 72 + sc + 8] = *(const bf16x8*)&kb[ksrc + 8];
            long vsrc = ((long)bh * 64 + sr) * 2048 + kt + sc;
            *(bf16x8*)&Vs[sr * 72 + sc]     = *(const bf16x8*)&vT[vsrc];
            *(bf16x8*)&Vs[sr * 72 + sc + 8] = *(const bf16x8*)&vT[vsrc + 8];
        }
        __syncthreads();
        // S = Q K^T  (per wave: 16 q-rows x 64 keys)
        f32x4 s[4] = {};
        for (int nt = 0; nt < 4; ++nt) {
            bf16x8 bk0 = *(const bf16x8*)&Ks[(nt * 16 + l16) * 72 + quad * 8];
            bf16x8 bk1 = *(const bf16x8*)&Ks[(nt * 16 + l16) * 72 + quad * 8 + 32];
            s[nt] = __builtin_amdgcn_mfma_f32_16x16x32_bf16(aq[0], bk0, s[nt], 0, 0, 0);
            s[nt] = __builtin_amdgcn_mfma_f32_16x16x32_bf16(aq[1], bk1, s[nt], 0, 0, 0);
        }
        // P = exp(S - scale); C-layout -> LDS (wave-private) -> A-layout
        unsigned short* Pw = &Ps[wave * 16 * 72];
        for (int nt = 0; nt < 4; ++nt)
            for (int r = 0; r < 4; ++r)
                Pw[(quad * 4 + r) * 72 + nt * 16 + l16] = f2bf(__expf(s[nt][r] - scale));
        bf16x8 ap0 = *(const bf16x8*)&Pw[l16 * 72 + quad * 8];
        bf16x8 ap1 = *(const bf16x8*)&Pw[l16 * 72 + quad * 8 + 32];
        // O += P V ; l += rowsum(P) via ones-fragment MFMA
        for (int nt = 0; nt < 4; ++nt) {
            bf16x8 bv0 = *(const bf16x8*)&Vs[(nt * 16 + l16) * 72 + quad * 8];
            bf16x8 bv1 = *(const bf16x8*)&Vs[(nt * 16 + l16) * 72 + quad * 8 + 32];
            o[nt] = __builtin_amdgcn_mfma_f32_16x16x32_bf16(ap0, bv0, o[nt], 0, 0, 0);
            o[nt] = __builtin_amdgcn_mfma_f32_16x16x32_bf16(ap1, bv1, o[nt], 0, 0, 0);
        }
        lacc = __builtin_amdgcn_mfma_f32_16x16x32_bf16(ap0, ones, lacc, 0, 0, 0);
        lacc = __builtin_amdgcn_mfma_f32_16x16x32_bf16(ap1, ones, lacc, 0, 0, 0);
    }
    // epilogue: divide by l, write attn[B,L,C] bf16
    const int b = bh >> 4;
    for (int r = 0; r < 4; ++r) {
        float inv = 1.0f / lacc[r];
        int lrow = q0 + wave * 16 + quad * 4 + r;
        long dst = (long)(b * 2048 + lrow) * 1024 + h * 64;
        for (int nt = 0; nt < 4; ++nt)
            attn[dst + nt * 16 + l16] = f2bf(o[nt][r] * inv);
    }
}

// ---------------------------------------------------------------------------
extern "C" void kernel_launch(void* const* d_in, const int* in_sizes, int n_in,
                              void* d_out, int out_size, void* d_ws, size_t ws_size,
                              hipStream_t stream) {
    const float* x    = (const float*)d_in[0];
    const float* Wqkv = (const float*)d_in[1];
    const float* qbia = (const float*)d_in[2];
    const float* vbia = (const float*)d_in[3];
    const float* sml  = (const float*)d_in[4];
    const float* Wp   = (const float*)d_in[5];
    const float* bp   = (const float*)d_in[6];

    char* ws = (char*)d_ws;
    unsigned short* qkv   = (unsigned short*)ws;                              // 8192*3072 bf16 (50.3MB)
    unsigned short* qbuf  = (unsigned short*)(ws + 50331648);                 // 16.8MB
    unsigned short* kbuf  = (unsigned short*)(ws + 50331648 + 16777216);      // 16.8MB
    unsigned short* vT    = (unsigned short*)(ws + 50331648 + 2 * 16777216);  // 16.8MB
    float*          bias3 = (float*)(ws + 50331648 + 3 * 16777216);           // 12KB
    unsigned short* attn  = qkv;   // reuse qkv region after q/k/v extracted
    float*          out   = (float*)d_out;

    hipLaunchKernelGGL(k_build_bias, dim3(12), dim3(256), 0, stream, qbia, vbia, bias3);
    hipLaunchKernelGGL((k_gemm_bt<true, false>), dim3(64, 24), dim3(256), 0, stream,
                       (const void*)x, Wqkv, bias3, (void*)qkv, 3072, 1024);
    hipLaunchKernelGGL(k_norm_qk, dim3(32768), dim3(256), 0, stream, qkv, sml, qbuf, kbuf);
    hipLaunchKernelGGL(k_vtrans, dim3(32, 64), dim3(256), 0, stream, qkv, vT);
    hipLaunchKernelGGL(k_attn, dim3(32, 64), dim3(256), 0, stream, qbuf, kbuf, vT, sml, attn);
    hipLaunchKernelGGL((k_gemm_bt<false, true>), dim3(64, 8), dim3(256), 0, stream,
                       (const void*)attn, Wp, bp, (void*)out, 1024, 1024);
}